// Round 8
// baseline (203.135 us; speedup 1.0000x reference)
//
#include <hip/hip_runtime.h>
#include <math.h>

#define BB 8
#define CC 1024
#define HH 56
#define WW 56
#define NB 256
#define NCLS 30
#define PLANE (HH * WW)              // 3136
#define NPART 64                     // gpart classes (49 blocks/class)
#define NCOLC 8                      // colhist copies (64 atomics/line depth)
#define GH_BLOCKS 3136               // 6,422,528 float4 / 2048 per block
#define F4_PER_BLOCK 2048            // 8 float4/thread, register-prefetched
#define QPP 784                      // float4 quads per plane
#define TB 8                         // tail grid

// ---------------------------------------------------------------------------
// Workspace layout (bytes):
//   colhist8 @ 0       : 458,752   u32[8][56][256]
//   gpart    @ 458,752 : 65,536    u32[64][256]
//   meta     @ 524,288 : 768       flag@u32[0], region@[1..3], bar@[64+i*16]
//   hist     @ 786,432 : 3,211,264 u32[3136][256]  (fallback only)
// ---------------------------------------------------------------------------
#define COL_U32 (NCOLC * HH * NB)                     // 114,688
#define GPART_OFF_U32 COL_U32
#define META_OFF_U32 (COL_U32 + NPART * NB)           // 131,072
#define ZERO_U32 (META_OFF_U32 + 192)                 // 131,264
#define ZERO_U4 (ZERO_U32 / 4)                        // 32,816
#define HIST_OFF 786432ull
#define FULL_NEED (HIST_OFF + (size_t)PLANE * NB * 4)

// ---------------------------------------------------------------------------
// Kernel 0: zero colhist8 + gpart + meta (contiguous, uint4 stores).
// ---------------------------------------------------------------------------
__global__ void zero_kernel(uint4* __restrict__ p) {
    const int i = blockIdx.x * 256 + threadIdx.x;  // grid 129*256 = 33,024
    if (i < ZERO_U4) p[i] = make_uint4(0u, 0u, 0u, 0u);
}

// ---------------------------------------------------------------------------
// Kernel 1: fused global 256-bin hist + row-0 per-column hists.
// R7 structure with ONE change: the 8-deep float4 prefetch is FORCED to
// materialize via an asm keep-alive (R6 counter evidence: VGPR_Count=32 ->
// the backend was register-minimizing and sinking each load next to its use,
// serializing the read path at ~1 outstanding load = R1's measured 61 us /
// 12% HBM). The asm consumes all 8 vectors before the side-effecting atomic
// loop, so all 8 global_load_dwordx4 issue back-to-back with a single
// s_waitcnt. __launch_bounds__(256,4): cap 128 VGPR, >=4 blocks/CU.
// ---------------------------------------------------------------------------
__global__ __launch_bounds__(256, 4) void ghist_kernel(const float* __restrict__ x,
                                                       unsigned* __restrict__ colhist8,
                                                       unsigned* __restrict__ gpart) {
    __shared__ unsigned lh[4 * NB];  // 4 KB
    const int tid = threadIdx.x;
    const int bid = blockIdx.x;
    lh[tid] = 0u; lh[NB + tid] = 0u; lh[2 * NB + tid] = 0u; lh[3 * NB + tid] = 0u;
    __syncthreads();

    const size_t base_f4 = (size_t)bid * F4_PER_BLOCK;
    const float4* __restrict__ xb = (const float4*)x + base_f4;
    float4 v[8];
#pragma unroll
    for (int it = 0; it < 8; ++it) v[it] = xb[it * 256 + tid];
    // Force all 8 loads issued & resident before any use (defeat load-sinking).
    asm volatile("" ::"v"(v[0].x), "v"(v[1].x), "v"(v[2].x), "v"(v[3].x),
                 "v"(v[4].x), "v"(v[5].x), "v"(v[6].x), "v"(v[7].x));

    unsigned* colmy = colhist8 + (bid & (NCOLC - 1)) * (HH * NB);
    int qm = (bid * F4_PER_BLOCK + tid) % QPP;  // quad idx within plane
    unsigned* wl = lh + ((tid >> 6) << 8);      // wave-private 256-bin hist
#pragma unroll
    for (int it = 0; it < 8; ++it) {
        const bool r0 = (qm < 14);              // quad lies in row 0
        const int li4 = qm << 2;                // plane-local element idx
        const float vv[4] = {v[it].x, v[it].y, v[it].z, v[it].w};
#pragma unroll
        for (int e = 0; e < 4; ++e) {
            const float f = vv[e];
            if (f >= 0.f && f <= 1.f) {         // histc: OOR dropped
                int bin = (int)(f * 256.f);     // floor (f>=0)
                if (bin > 255) bin = 255;       // v==1 -> last bin
                atomicAdd(&wl[bin], 1u);
                if (r0) atomicAdd(&colmy[(li4 + e) * NB + bin], 1u);
            }
        }
        qm += 256;
        if (qm >= QPP) qm -= QPP;
    }
    __syncthreads();
    const unsigned s = lh[tid] + lh[NB + tid] + lh[2 * NB + tid] + lh[3 * NB + tid];
    if (s) atomicAdd(&gpart[((bid & (NPART - 1)) << 8) + tid], s);
}

// ---------------------------------------------------------------------------
// Wave / entropy helpers (identical reduction order to the verified kernels).
// ---------------------------------------------------------------------------
__device__ __forceinline__ float wave_sum(float v) {
#pragma unroll
    for (int off = 32; off > 0; off >>= 1) v += __shfl_xor(v, off);
    return v;
}

__device__ __forceinline__ float ilook(const unsigned* __restrict__ integ,
                                       int a, int b, int bin) {
    return (a == 0 || b == 0)
               ? 0.f
               : (float)integ[((size_t)((a - 1) * WW + (b - 1))) * NB + bin];
}

__device__ float region_ent(const unsigned* __restrict__ integ, int lane,
                            int xd, int ys, int yd) {
    float hb[4];
    float hs = 0.f;
#pragma unroll
    for (int k = 0; k < 4; k++) {
        const int bin = lane + 64 * k;
        const float hv = ilook(integ, xd, yd, bin) - ilook(integ, xd, ys, bin);
        hb[k] = hv;
        hs += hv;
    }
    hs = wave_sum(hs);
    float e = 0.f;
#pragma unroll
    for (int k = 0; k < 4; k++) {
        const float p = hb[k] / hs;
        e += p * log2f(p + 1e-9f);
    }
    return -wave_sum(e);
}

// 8-block counting barrier, RMW-polled (R4 lesson: never relaxed loads).
// Cold path only (fallback); 16 fences total, harmless there.
__device__ __forceinline__ void bsync8(unsigned* __restrict__ ctr) {
    __syncthreads();
    if (threadIdx.x == 0) {
        __threadfence();                   // release
        atomicAdd(ctr, 1u);
        while (atomicAdd(ctr, 0u) < TB) __builtin_amdgcn_s_sleep(32);
    }
    __syncthreads();
    __threadfence();                       // acquire
}

// ---------------------------------------------------------------------------
// Kernel 2: tail, 8 blocks x 256. Block 0: decide -> release-publish
// flag/region (ONE fence). Blocks 1..7: RMW-poll flag (~3 us). Then
// [flag==2: 8-block fallback EKLM, never taken on bench data] and fused
// pool+FC (block = batch).
// ---------------------------------------------------------------------------
__global__ __launch_bounds__(256) void tail_kernel(
    const float* __restrict__ x, const float* __restrict__ wfc,
    const unsigned* __restrict__ colhist8, const unsigned* __restrict__ gpart,
    unsigned* __restrict__ meta, unsigned* __restrict__ hist,
    float* __restrict__ out, int have_hist) {
    __shared__ float shf[CC + 240];  // ent_s (56) then pl_s[1024]+red[240]
    __shared__ unsigned sfl;
    __shared__ int sreg[3];
    const int tid = threadIdx.x;
    const int bid = blockIdx.x;
    unsigned* flag = meta;
    int* region = (int*)(meta + 1);
    unsigned* bar = meta + 64;       // counters at bar[i*16]

    if (bid == 0) {
        // ---- decide (identical math to verified rounds) ----
        float* ent_s = shf;
        const int lane = tid & 63;
        const int wv = tid >> 6;
        for (int w = wv; w < WW; w += 4) {
            float hb[4], hs = 0.f;
#pragma unroll
            for (int k = 0; k < 4; k++) {
                const int bin = lane + 64 * k;
                unsigned t = 0;
#pragma unroll
                for (int s = 0; s < NCOLC; ++s)
                    t += colhist8[s * (HH * NB) + w * NB + bin];
                hb[k] = (float)t;
                hs += hb[k];
            }
            hs = wave_sum(hs);
            float e = 0.f;
#pragma unroll
            for (int k = 0; k < 4; k++) {
                const float p = hb[k] / hs;
                e += p * log2f(p + 1e-9f);
            }
            e = -wave_sum(e);
            if (lane == 0) ent_s[w] = e;
        }
        __syncthreads();
        if (tid < 64) {
            const int ln = tid;
            float best = -3.0e38f;
            int bestw = 0;
            for (int w = 0; w < WW; ++w) {
                const float e = ent_s[w];
                if (e > best) { best = e; bestw = w; }  // first max (argmax)
            }
            float hb[4], hs = 0.f;
#pragma unroll
            for (int k = 0; k < 4; k++) {
                const int bin = ln + 64 * k;
                unsigned t = 0;
#pragma unroll
                for (int p = 0; p < NPART; ++p) t += gpart[(p << 8) + bin];
                hb[k] = (float)t;
                hs += hb[k];
            }
            hs = wave_sum(hs);
            float e = 0.f;
#pragma unroll
            for (int k = 0; k < 4; k++) {
                const float p = hb[k] / hs;
                e += p * log2f(p + 1e-9f);
            }
            const float total_ent = -wave_sum(e);
            const float Ts0 = best / total_ent;  // cell ent == column ent
            if (ln == 0) {
                sreg[0] = 1; sreg[1] = bestw; sreg[2] = bestw + 1;
                region[0] = 1;
                region[1] = bestw;
                region[2] = bestw + 1;
                __threadfence();  // release region before flag
                const unsigned v = (Ts0 >= 0.9f) ? 1u : 2u;
                atomicExch(flag, v);
                sfl = v;
            }
        }
        __syncthreads();
    } else {
        if (tid == 0) {
            unsigned f;
            while ((f = atomicAdd(flag, 0u)) == 0u) __builtin_amdgcn_s_sleep(16);
            sfl = f;
            sreg[0] = (int)atomicAdd((unsigned*)&region[0], 0u);
            sreg[1] = (int)atomicAdd((unsigned*)&region[1], 0u);
            sreg[2] = (int)atomicAdd((unsigned*)&region[2], 0u);
        }
        __syncthreads();
    }

    // ---- fallback (correctness-only, slow; never taken on bench data) ----
    if (sfl == 2u && have_hist) {
        const int gtid = bid * 256 + tid;  // 0..2047
        // F0: zero per-cell hist
        for (int i = gtid; i < PLANE * NB; i += TB * 256) hist[i] = 0u;
        bsync8(&bar[0 * 16]);
        // F1: accumulate per-cell hists via global atomics
        for (int c = bid; c < GH_BLOCKS; c += TB) {
            const float4* __restrict__ xb2 =
                (const float4*)x + (size_t)c * F4_PER_BLOCK;
            int qm2 = (c * F4_PER_BLOCK + tid) % QPP;
            for (int it = 0; it < 8; ++it) {
                const float4 v2 = xb2[it * 256 + tid];
                const int cell4 = qm2 << 2;
                const float vv[4] = {v2.x, v2.y, v2.z, v2.w};
                for (int e = 0; e < 4; ++e) {
                    const float f = vv[e];
                    if (f >= 0.f && f <= 1.f) {
                        int bin = (int)(f * 256.f);
                        if (bin > 255) bin = 255;
                        atomicAdd(&hist[(size_t)(cell4 + e) * NB + bin], 1u);
                    }
                }
                qm2 += 256;
                if (qm2 >= QPP) qm2 -= QPP;
            }
        }
        bsync8(&bar[1 * 16]);
        // F2: inclusive prefix along w
        for (int i2 = gtid; i2 < HH * NB; i2 += TB * 256) {
            const int h = i2 >> 8, b = i2 & 255;
            unsigned* base = hist + (size_t)h * WW * NB + b;
            unsigned c2 = 0;
            for (int w = 0; w < WW; ++w) {
                c2 += base[(size_t)w * NB];
                base[(size_t)w * NB] = c2;
            }
        }
        bsync8(&bar[2 * 16]);
        // F3: inclusive prefix along h
        for (int i2 = gtid; i2 < WW * NB; i2 += TB * 256) {
            const int w = i2 >> 8, b = i2 & 255;
            unsigned* base = hist + (size_t)w * NB + b;
            unsigned c2 = 0;
            for (int h = 0; h < HH; ++h) {
                c2 += base[(size_t)h * WW * NB];
                base[(size_t)h * WW * NB] = c2;
            }
        }
        bsync8(&bar[3 * 16]);
        // F4: greedy loop (block 0 wave 0), from fast-path region
        if (bid == 0 && tid < 64) {
            const int lane = tid;
            const float total_ent = region_ent(hist, lane, HH, 0, WW);
            int xd = region[0], ys = region[1], yd = region[2];
            float Ts = region_ent(hist, lane, xd, ys, yd) / total_ent;
            bool done = false;
            int iter = 0;
            while (Ts < 0.9f && !done && iter < 1000) {
                iter++;
                const float e_cur = region_ent(hist, lane, xd, ys, yd);
                const int ysm = (ys - 1 < 0) ? 0 : ys - 1;
                const int ydp = (yd + 1 > WW) ? WW : yd + 1;
                const bool c1 = (xd + 1 < HH) &&
                                (region_ent(hist, lane, xd + 1, ys, yd) > e_cur);
                const bool c2 = !c1 && (ys - 1 >= 0) &&
                                (region_ent(hist, lane, xd, ysm, yd) > e_cur);
                const bool c3 = !c1 && !c2 && (yd + 1 < WW) &&
                                (region_ent(hist, lane, xd, ys, ydp) > e_cur);
                if (c1) xd = xd + 1;
                else if (c2) ys = ys - 1;
                else if (c3) yd = yd + 1;
                done = !(c1 || c2 || c3);
                Ts = region_ent(hist, lane, xd, ys, yd) / total_ent;
            }
            if (lane == 0) { region[0] = xd; region[1] = ys; region[2] = yd; }
        }
        bsync8(&bar[4 * 16]);
        if (tid == 0) {
            sreg[0] = (int)atomicAdd((unsigned*)&region[0], 0u);
            sreg[1] = (int)atomicAdd((unsigned*)&region[1], 0u);
            sreg[2] = (int)atomicAdd((unsigned*)&region[2], 0u);
        }
        __syncthreads();
    }

    // ---- fused pool + FC (block = batch index) ----
    const int xd = sreg[0], ys = sreg[1], yd = sreg[2];
    const int Wd = yd - ys;
    const int n = xd * Wd;
    const float area = fmaxf((float)n, 1.f);
    float* pl_s = shf;            // 1024 floats (ent_s dead)
    float* red = shf + CC;        // 240 floats
    __syncthreads();
    const float* __restrict__ xb = x + (size_t)bid * CC * PLANE;
#pragma unroll
    for (int k = 0; k < 4; ++k) {
        const int c = tid + k * 256;
        const float* plane = xb + (size_t)c * PLANE;
        float s = 0.f;
        for (int j = 0; j < n; ++j) {
            const int r = j / Wd;
            const int cc2 = ys + (j - r * Wd);
            s += plane[r * WW + cc2];
        }
        pl_s[c] = s / area;
    }
    __syncthreads();
    if (tid < 240) {
        const int chunk = tid / NCLS;
        const int nn = tid - chunk * NCLS;
        const float* pv = pl_s + chunk * 128;
        const float* wv2 = wfc + (size_t)(chunk * 128) * NCLS + nn;
        float a0 = 0.f, a1 = 0.f, a2 = 0.f, a3 = 0.f;
        for (int c = 0; c < 128; c += 4) {
            a0 += pv[c + 0] * wv2[(c + 0) * NCLS];
            a1 += pv[c + 1] * wv2[(c + 1) * NCLS];
            a2 += pv[c + 2] * wv2[(c + 2) * NCLS];
            a3 += pv[c + 3] * wv2[(c + 3) * NCLS];
        }
        red[tid] = (a0 + a1) + (a2 + a3);
    }
    __syncthreads();
    if (tid < NCLS) {
        float s = 0.f;
#pragma unroll
        for (int ch2 = 0; ch2 < 8; ++ch2) s += red[ch2 * NCLS + tid];
        out[bid * NCLS + tid] = s;
    }
}

// ---------------------------------------------------------------------------
extern "C" void kernel_launch(void* const* d_in, const int* in_sizes, int n_in,
                              void* d_out, int out_size, void* d_ws, size_t ws_size,
                              hipStream_t stream) {
    const float* x = (const float*)d_in[0];    // [8,1024,56,56]
    const float* wfc = (const float*)d_in[1];  // [1024,30]
    float* out = (float*)d_out;                // [8,30]

    unsigned char* ws = (unsigned char*)d_ws;
    unsigned* colhist8 = (unsigned*)ws;                      // 458,752 B
    unsigned* gpart = (unsigned*)(ws + GPART_OFF_U32 * 4);   // 65,536 B
    unsigned* meta = (unsigned*)(ws + META_OFF_U32 * 4);     // 768 B
    unsigned* hist = (unsigned*)(ws + HIST_OFF);             // fallback only
    const int have_hist = (ws_size >= FULL_NEED) ? 1 : 0;

    zero_kernel<<<129, 256, 0, stream>>>((uint4*)ws);
    ghist_kernel<<<GH_BLOCKS, 256, 0, stream>>>(x, colhist8, gpart);
    tail_kernel<<<TB, 256, 0, stream>>>(x, wfc, colhist8, gpart, meta, hist,
                                        out, have_hist);
}

// Round 9
// 177.755 us; speedup vs baseline: 1.1428x; 1.1428x over previous
//
#include <hip/hip_runtime.h>
#include <math.h>

#define BB 8
#define CC 1024
#define HH 56
#define WW 56
#define NB 256
#define NCLS 30
#define BC (BB * CC)                 // 8192 planes
#define PLANE (HH * WW)              // 3136
#define NWORD (NB / 2)               // 128 packed u16-pairs (fallback)
#define CELLW (PLANE * NWORD)        // 401408 packed words
#define SLICES 16
#define PL_PER_SLICE (BC / SLICES)   // 512 planes
#define NPART 16                     // partial global hists
#define GH_BLOCKS 784                // pipelined: 4 chunks per block
#define GH_CHUNKS 4
#define F4_PER_BLOCK 2048            // float4 per chunk (8/thread)
#define FB_BLOCKS 256                // fallback grid

// ---------------------------------------------------------------------------
// Workspace layout — byte-identical to the measured-best round-3 kernel:
//   ps       @ 0          25,690,112 B  (fallback per-slice packed hists)
//   colhist  @ 0              57,344 B  (u32[56][256]; aliases ps head — dead
//   gpart    @ 57,344         16,384 B   before fallback overwrites ps)
//   hist     @ 25,690,112  3,211,264 B  (fallback integral hists)
//   meta     @ 28,901,376        64 B  (region @+0, flag @+16, bar[8] @+32)
// ---------------------------------------------------------------------------
#define FULL_NEED 28934400ull
#define META_OFF 28901376ull

// ---------------------------------------------------------------------------
// Kernel 0: zero colhist + gpart (18,432 u32 contiguous) + barrier counters.
// ---------------------------------------------------------------------------
__global__ void zero_kernel(unsigned* __restrict__ p, unsigned* __restrict__ bar) {
    p[blockIdx.x * 256 + threadIdx.x] = 0u;  // grid 72*256 = 18432 exact
    if (blockIdx.x == 0 && threadIdx.x < 8) bar[threadIdx.x] = 0u;
}

// ---------------------------------------------------------------------------
// Kernel 1: fused global 256-bin hist + row-0 per-column hists.
// ONLY change vs the 169.8-us round-3 kernel: software pipeline. 784 blocks,
// 4 chunks each; each iteration ISSUES the next chunk's 8 global_load_dwordx4
// before the current chunk's 32 LDS atomics, so the s_waitcnt for chunk k+1
// lands after chunk k's atomic work — 8 loads structurally in flight
// (dependency-enforced overlap; R8 lesson: asm keep-alives don't give this).
// colhist: single copy, direct global atomics for row-0 quads (~2% of elems).
// gpart flush: 784 blocks -> 4x fewer atomics, 49-deep chains per class.
// ---------------------------------------------------------------------------
__global__ __launch_bounds__(256) void ghist_kernel(const float* __restrict__ x,
                                                    unsigned* __restrict__ colhist,
                                                    unsigned* __restrict__ gpart) {
    __shared__ unsigned lh[4 * NB];  // 4 KB
    const int tid = threadIdx.x;
    const int bid = blockIdx.x;
    lh[tid] = 0u; lh[NB + tid] = 0u; lh[2 * NB + tid] = 0u; lh[3 * NB + tid] = 0u;
    __syncthreads();

    const float4* __restrict__ xb = (const float4*)x;
    unsigned* wl = lh + ((tid >> 6) << 8);  // this wave's private hist

    float4 cur[8];
    {
        const size_t b0 = (size_t)bid * F4_PER_BLOCK;
#pragma unroll
        for (int it = 0; it < 8; ++it) cur[it] = xb[b0 + it * 256 + tid];
    }
#pragma unroll
    for (int k = 0; k < GH_CHUNKS; ++k) {
        const int cidx = bid + k * GH_BLOCKS;  // chunk id, strided
        float4 nxt[8];
        if (k + 1 < GH_CHUNKS) {
            const size_t bn = (size_t)(bid + (k + 1) * GH_BLOCKS) * F4_PER_BLOCK;
#pragma unroll
            for (int it = 0; it < 8; ++it) nxt[it] = xb[bn + it * 256 + tid];
        }
#pragma unroll
        for (int it = 0; it < 8; ++it) {
            const int j = it * 256 + tid;
            const int e0 = (cidx * F4_PER_BLOCK + j) * 4;  // element idx <25.7M
            const int pl = e0 / PLANE;        // const-div -> magic mul
            const int li = e0 - pl * PLANE;   // plane-local, multiple of 4
            const bool r0 = (li < WW);        // whole float4 is row 0
            const float vv[4] = {cur[it].x, cur[it].y, cur[it].z, cur[it].w};
#pragma unroll
            for (int e = 0; e < 4; ++e) {
                const float f = vv[e];
                if (f >= 0.f && f <= 1.f) {        // histc: OOR dropped
                    int bin = (int)(f * 256.f);    // floor (f>=0)
                    if (bin > 255) bin = 255;      // v==1 -> last bin
                    atomicAdd(&wl[bin], 1u);
                    if (r0) atomicAdd(&colhist[(li + e) * NB + bin], 1u);
                }
            }
        }
        if (k + 1 < GH_CHUNKS) {
#pragma unroll
            for (int it = 0; it < 8; ++it) cur[it] = nxt[it];
        }
    }
    __syncthreads();
    const unsigned s = lh[tid] + lh[NB + tid] + lh[2 * NB + tid] + lh[3 * NB + tid];
    if (s) atomicAdd(&gpart[((bid & (NPART - 1)) << 8) + tid], s);
}

// ---------------------------------------------------------------------------
// Wave / entropy helpers (identical reduction order to the verified kernels).
// ---------------------------------------------------------------------------
__device__ __forceinline__ float wave_sum(float v) {
#pragma unroll
    for (int off = 32; off > 0; off >>= 1) v += __shfl_xor(v, off);
    return v;
}

__device__ __forceinline__ float ilook(const unsigned* __restrict__ integ,
                                       int a, int b, int bin) {
    return (a == 0 || b == 0)
               ? 0.f
               : (float)integ[((size_t)((a - 1) * WW + (b - 1))) * NB + bin];
}

__device__ float region_ent(const unsigned* __restrict__ integ, int lane,
                            int xd, int ys, int yd) {
    float hb[4];
    float hs = 0.f;
#pragma unroll
    for (int k = 0; k < 4; k++) {
        const int bin = lane + 64 * k;
        const float hv = ilook(integ, xd, yd, bin) - ilook(integ, xd, ys, bin);
        hb[k] = hv;
        hs += hv;
    }
    hs = wave_sum(hs);
    float e = 0.f;
#pragma unroll
    for (int k = 0; k < 4; k++) {
        const float p = hb[k] / hs;
        e += p * log2f(p + 1e-9f);
    }
    return -wave_sum(e);
}

// ---------------------------------------------------------------------------
// Kernel 2: fast decide — verbatim round-3 (1 block x 1024). ent_y from
// colhist, argmax -> ys0; total_ent from the 16 gpart partials;
// Ts0 = ent_y[ys0]/total_ent (single-cell == column entropy, same counts).
// flag=1 done, flag=2 fallback continues.
// ---------------------------------------------------------------------------
__global__ __launch_bounds__(1024) void decide_fast_kernel(
    const unsigned* __restrict__ colhist, const unsigned* __restrict__ gpart,
    int* __restrict__ region, unsigned* __restrict__ flag) {
    __shared__ float ent_s[WW];
    const int tid = threadIdx.x;
    const int lane = tid & 63;
    const int wv = tid >> 6;

    for (int w = wv; w < WW; w += 16) {
        float hb[4], hs = 0.f;
#pragma unroll
        for (int k = 0; k < 4; k++) {
            const int bin = lane + 64 * k;
            hb[k] = (float)colhist[w * NB + bin];
            hs += hb[k];
        }
        hs = wave_sum(hs);
        float e = 0.f;
#pragma unroll
        for (int k = 0; k < 4; k++) {
            const float p = hb[k] / hs;
            e += p * log2f(p + 1e-9f);
        }
        e = -wave_sum(e);
        if (lane == 0) ent_s[w] = e;
    }
    __syncthreads();
    if (wv != 0) return;

    float best = -3.0e38f;
    int bestw = 0;
    for (int w = 0; w < WW; ++w) {
        const float e = ent_s[w];
        if (e > best) { best = e; bestw = w; }  // strict > keeps FIRST max
    }

    float hb[4], hs = 0.f;
#pragma unroll
    for (int k = 0; k < 4; k++) {
        const int bin = lane + 64 * k;
        unsigned t = 0;
#pragma unroll
        for (int p = 0; p < NPART; ++p) t += gpart[(p << 8) + bin];
        hb[k] = (float)t;
        hs += hb[k];
    }
    hs = wave_sum(hs);
    float e = 0.f;
#pragma unroll
    for (int k = 0; k < 4; k++) {
        const float p = hb[k] / hs;
        e += p * log2f(p + 1e-9f);
    }
    const float total_ent = -wave_sum(e);

    const float Ts0 = best / total_ent;
    if (lane == 0) {
        region[0] = 1;          // xd
        region[1] = bestw;      // ys
        region[2] = bestw + 1;  // yd
        *flag = (Ts0 >= 0.9f) ? 1u : 2u;
    }
}

// ---------------------------------------------------------------------------
// Software grid barrier (fallback path only; never runs on flag==1).
// RMW-polled at the coherent point (round-4 lesson: no relaxed loads).
// ---------------------------------------------------------------------------
__device__ __forceinline__ void soft_grid_sync(unsigned* __restrict__ bar,
                                               int idx, unsigned nb) {
    __syncthreads();
    if (threadIdx.x == 0) {
        __threadfence();                       // release
        atomicAdd(&bar[idx], 1u);
        while (atomicAdd(&bar[idx], 0u) < nb) {
            __builtin_amdgcn_s_sleep(8);
        }
    }
    __syncthreads();
    __threadfence();                           // acquire
}

// ---------------------------------------------------------------------------
// Kernel 3: fallback — verbatim round-3. Ordinary launch, gated on flag==2
// (bench data: flag==1, every block exits immediately, ~2 us dispatch).
// ---------------------------------------------------------------------------
__global__ __launch_bounds__(256) void fallback_kernel(
    const float* __restrict__ x, unsigned* __restrict__ ps,
    unsigned* __restrict__ hist, int* __restrict__ region,
    const unsigned* __restrict__ flag, unsigned* __restrict__ bar) {
    if (*flag == 1u) return;  // all blocks exit together; no barrier reached
    __shared__ unsigned lh[HH * NWORD];  // 7168 words, u16-packed (28 KB)
    const int tid = threadIdx.x;
    const int gtid = blockIdx.x * 256 + tid;

    // phase 1: per-(h,slice) tile histograms -> ps (non-atomic, tile-owned)
    for (int t = blockIdx.x; t < HH * SLICES; t += FB_BLOCKS) {
        const int h = t % HH;
        const int slice = t / HH;
        for (int i = tid; i < HH * NWORD; i += 256) lh[i] = 0u;
        __syncthreads();
        const float* __restrict__ xb =
            x + (size_t)(slice * PL_PER_SLICE) * PLANE + h * WW;
        for (int it = 0; it < 28; ++it) {  // 512 planes * 14 float4 / 256
            const int j = it * 256 + tid;
            const int bcl = j / 14;
            const int wq = j - bcl * 14;
            const float4 v = *(const float4*)(xb + (size_t)bcl * PLANE + wq * 4);
            const float vv[4] = {v.x, v.y, v.z, v.w};
#pragma unroll
            for (int e = 0; e < 4; ++e) {
                const float f = vv[e];
                if (f >= 0.f && f <= 1.f) {
                    int bin = (int)(f * 256.f);
                    if (bin > 255) bin = 255;
                    atomicAdd(&lh[(wq * 4 + e) * NWORD + (bin >> 1)],
                              1u << ((bin & 1) << 4));
                }
            }
        }
        __syncthreads();
        unsigned* g = ps + (size_t)slice * CELLW + (size_t)h * WW * NWORD;
        for (int i = tid; i < HH * NWORD; i += 256) g[i] = lh[i];
        __syncthreads();
    }
    soft_grid_sync(bar, 0, FB_BLOCKS);

    // phase 2: reduce 16 slices + unpack -> hist u32 [h][w][256]
    for (int idx = gtid; idx < CELLW; idx += FB_BLOCKS * 256) {
        unsigned s = 0;
#pragma unroll
        for (int sl = 0; sl < SLICES; ++sl) s += ps[(size_t)sl * CELLW + idx];
        ((uint2*)hist)[idx] = make_uint2(s & 0xffffu, s >> 16);
    }
    soft_grid_sync(bar, 1, FB_BLOCKS);

    // phase 3: inclusive prefix along w (register-staged)
    if (gtid < HH * NB) {
        const int h = gtid >> 8, b = gtid & 255;
        unsigned* base = hist + (size_t)h * WW * NB + b;
        unsigned v[WW];
#pragma unroll
        for (int w = 0; w < WW; ++w) v[w] = base[(size_t)w * NB];
        unsigned c = 0;
#pragma unroll
        for (int w = 0; w < WW; ++w) { c += v[w]; base[(size_t)w * NB] = c; }
    }
    soft_grid_sync(bar, 2, FB_BLOCKS);

    // phase 4: inclusive prefix along h
    if (gtid < WW * NB) {
        const int w = gtid >> 8, b = gtid & 255;
        unsigned* base = hist + (size_t)w * NB + b;
        unsigned v[HH];
#pragma unroll
        for (int h = 0; h < HH; ++h) v[h] = base[(size_t)h * WW * NB];
        unsigned c = 0;
#pragma unroll
        for (int h = 0; h < HH; ++h) { c += v[h]; base[(size_t)h * WW * NB] = c; }
    }
    soft_grid_sync(bar, 3, FB_BLOCKS);

    // phase 5: greedy loop, block 0 wave 0, starting from fast-path region
    if (blockIdx.x == 0 && tid < 64) {
        const int lane = tid;
        const float total_ent = region_ent(hist, lane, HH, 0, WW);
        int xd = region[0], ys = region[1], yd = region[2];
        float Ts = region_ent(hist, lane, xd, ys, yd) / total_ent;
        bool done = false;
        int iter = 0;
        while (Ts < 0.9f && !done && iter < 1000) {
            iter++;
            const float e_cur = region_ent(hist, lane, xd, ys, yd);
            const int ysm = (ys - 1 < 0) ? 0 : ys - 1;
            const int ydp = (yd + 1 > WW) ? WW : yd + 1;
            const bool c1 = (xd + 1 < HH) &&
                            (region_ent(hist, lane, xd + 1, ys, yd) > e_cur);
            const bool c2 = !c1 && (ys - 1 >= 0) &&
                            (region_ent(hist, lane, xd, ysm, yd) > e_cur);
            const bool c3 = !c1 && !c2 && (yd + 1 < WW) &&
                            (region_ent(hist, lane, xd, ys, ydp) > e_cur);
            if (c1) xd = xd + 1;
            else if (c2) ys = ys - 1;
            else if (c3) yd = yd + 1;
            done = !(c1 || c2 || c3);
            Ts = region_ent(hist, lane, xd, ys, yd) / total_ent;
        }
        if (lane == 0) {
            region[0] = xd;
            region[1] = ys;
            region[2] = yd;
        }
    }
}

// ---------------------------------------------------------------------------
// Kernel 4: fused pool + FC — verbatim round-3. Block = batch b.
// ---------------------------------------------------------------------------
__global__ __launch_bounds__(256) void fc_kernel(const float* __restrict__ x,
                                                 const int* __restrict__ region,
                                                 const float* __restrict__ wfc,
                                                 float* __restrict__ out) {
    __shared__ float pl_s[CC];
    __shared__ float red[240];
    const int b = blockIdx.x;
    const int t = threadIdx.x;
    const int xd = region[0], ys = region[1], yd = region[2];
    const int Wd = yd - ys;
    const int n = xd * Wd;
    const float area = fmaxf((float)n, 1.f);
    const float* __restrict__ xb = x + (size_t)b * CC * PLANE;
#pragma unroll
    for (int k = 0; k < 4; ++k) {
        const int c = t + k * 256;
        const float* plane = xb + (size_t)c * PLANE;
        float s = 0.f;
        for (int j = 0; j < n; ++j) {
            const int r = j / Wd;
            const int cc2 = ys + (j - r * Wd);
            s += plane[r * WW + cc2];
        }
        pl_s[c] = s / area;
    }
    __syncthreads();
    if (t < 240) {
        const int chunk = t / NCLS;
        const int nn = t - chunk * NCLS;
        const float* pv = pl_s + chunk * 128;
        const float* wv = wfc + (size_t)(chunk * 128) * NCLS + nn;
        float a0 = 0.f, a1 = 0.f, a2 = 0.f, a3 = 0.f;
        for (int c = 0; c < 128; c += 4) {
            a0 += pv[c + 0] * wv[(c + 0) * NCLS];
            a1 += pv[c + 1] * wv[(c + 1) * NCLS];
            a2 += pv[c + 2] * wv[(c + 2) * NCLS];
            a3 += pv[c + 3] * wv[(c + 3) * NCLS];
        }
        red[t] = (a0 + a1) + (a2 + a3);
    }
    __syncthreads();
    if (t < NCLS) {
        float s = 0.f;
#pragma unroll
        for (int ch = 0; ch < 8; ++ch) s += red[ch * NCLS + t];
        out[b * NCLS + t] = s;
    }
}

// ---------------------------------------------------------------------------
extern "C" void kernel_launch(void* const* d_in, const int* in_sizes, int n_in,
                              void* d_out, int out_size, void* d_ws, size_t ws_size,
                              hipStream_t stream) {
    const float* x = (const float*)d_in[0];    // [8,1024,56,56]
    const float* wfc = (const float*)d_in[1];  // [1024,30]
    float* out = (float*)d_out;                // [8,30]

    unsigned char* ws = (unsigned char*)d_ws;
    const bool full = (ws_size >= FULL_NEED);

    unsigned* colhist = (unsigned*)ws;                 // 57,344 B
    unsigned* gpart = (unsigned*)(ws + 57344);         // 16,384 B
    unsigned* ps = (unsigned*)ws;                      // fallback (aliases)
    unsigned* hist = (unsigned*)(ws + (size_t)SLICES * CELLW * 4);  // fallback
    int* region;
    unsigned* flag;
    unsigned* bar;
    if (full) {
        unsigned char* meta = ws + META_OFF;
        region = (int*)meta;
        flag = (unsigned*)(meta + 16);
        bar = (unsigned*)(meta + 32);
    } else {  // tiny-ws: fast path only (stats end @73,728)
        region = (int*)(ws + 73728);
        flag = (unsigned*)(ws + 73728 + 16);
        bar = (unsigned*)(ws + 73728 + 32);
    }

    zero_kernel<<<72, 256, 0, stream>>>(colhist, bar);  // colhist+gpart contig
    ghist_kernel<<<GH_BLOCKS, 256, 0, stream>>>(x, colhist, gpart);
    decide_fast_kernel<<<1, 1024, 0, stream>>>(colhist, gpart, region, flag);
    if (full) {
        fallback_kernel<<<FB_BLOCKS, 256, 0, stream>>>(x, ps, hist, region,
                                                       flag, bar);
    }
    fc_kernel<<<BB, 256, 0, stream>>>(x, region, wfc, out);
}